// Round 2
// baseline (459.474 us; speedup 1.0000x reference)
//
#include <hip/hip_runtime.h>
#include <stdint.h>

#define NCLUST 8192
#define BATCH 256
#define DIM 1024
#define NFEAT 65536
#define TEMP_INV 20.0f
#define TOPP 0.1f
#define EPSC 1e-6f
#define CAP 64  // max rows per cluster slab; labels ~Poisson(8) over 8192 clusters (max ~30)

typedef __attribute__((ext_vector_type(8))) short short8;
typedef __attribute__((ext_vector_type(4))) float floatx4;

__device__ __forceinline__ unsigned short f2bf(float f) {
    uint32_t u = __float_as_uint(f);
    uint32_t r = u + 0x7FFFu + ((u >> 16) & 1u);
    return (unsigned short)(r >> 16);
}

__device__ __forceinline__ float block_sum(float v, float* lds4) {
    for (int o = 32; o > 0; o >>= 1) v += __shfl_down(v, o, 64);
    __syncthreads();                       // protect lds4 from previous use
    if ((threadIdx.x & 63) == 0) lds4[threadIdx.x >> 6] = v;
    __syncthreads();
    return lds4[0] + lds4[1] + lds4[2] + lds4[3];
}

// ---------------- K0: zero counts + output ----------------
__global__ void k_init(int* counts, float* out) {
    int i = blockIdx.x * 256 + threadIdx.x;
    if (i < NCLUST) counts[i] = 0;
    if (i == 0) out[0] = 0.0f;
}

// ---------------- K1: fused scatter + L2-normalize ----------------
// Block b: scatters labels[b*256 .. +255] into per-cluster slabs AND normalizes
// results row b -> bf16. counts doubles as histogram (final value) and cursor.
__global__ void k_prep(const int* __restrict__ labels, int* __restrict__ counts,
                       int* __restrict__ idxlist,
                       const float* __restrict__ results, unsigned short* __restrict__ inputsB) {
    __shared__ float lds4[4];
    int b = blockIdx.x, t = threadIdx.x;
    // scatter part
    int n = b * 256 + t;
    int l = labels[n];
    int pos = atomicAdd(&counts[l], 1);
    if (pos < CAP) idxlist[l * CAP + pos] = n;
    // norm part
    const float4* rp = (const float4*)(results + (size_t)b * DIM);
    float4 v = rp[t];
    float ss = v.x * v.x + v.y * v.y + v.z * v.z + v.w * v.w;
    float S = block_sum(ss, lds4);
    float rn = rsqrtf(S);
    ushort4 o;
    o.x = f2bf(v.x * rn); o.y = f2bf(v.y * rn); o.z = f2bf(v.z * rn); o.w = f2bf(v.w * rn);
    *(ushort4*)(inputsB + (size_t)b * DIM + t * 4) = o;
}

// ---------------- K2: per-cluster feature sum, scale by 1/(TEMP*n), cast bf16 ----------------
__global__ __launch_bounds__(256) void k_csum(const float* __restrict__ features,
                                              const int* __restrict__ counts,
                                              const int* __restrict__ idxlist,
                                              unsigned short* __restrict__ FsumB) {
    int c = blockIdx.x, t = threadIdx.x;
    int cnt = counts[c];
    if (cnt > CAP) cnt = CAP;
    const int* lp = idxlist + c * CAP;
    float a0x = 0.f, a0y = 0.f, a0z = 0.f, a0w = 0.f;
    float a1x = 0.f, a1y = 0.f, a1z = 0.f, a1w = 0.f;
    float a2x = 0.f, a2y = 0.f, a2z = 0.f, a2w = 0.f;
    float a3x = 0.f, a3y = 0.f, a3z = 0.f, a3w = 0.f;
    int j = 0;
    for (; j + 4 <= cnt; j += 4) {
        int4 q = *(const int4*)(lp + j);   // 16B-aligned: CAP*4 = 256B slabs, j%4==0
        float4 v0 = ((const float4*)(features + (size_t)q.x * DIM))[t];
        float4 v1 = ((const float4*)(features + (size_t)q.y * DIM))[t];
        float4 v2 = ((const float4*)(features + (size_t)q.z * DIM))[t];
        float4 v3 = ((const float4*)(features + (size_t)q.w * DIM))[t];
        a0x += v0.x; a0y += v0.y; a0z += v0.z; a0w += v0.w;
        a1x += v1.x; a1y += v1.y; a1z += v1.z; a1w += v1.w;
        a2x += v2.x; a2y += v2.y; a2z += v2.z; a2w += v2.w;
        a3x += v3.x; a3y += v3.y; a3z += v3.z; a3w += v3.w;
    }
    for (; j < cnt; j++) {
        int r0 = lp[j];
        float4 v0 = ((const float4*)(features + (size_t)r0 * DIM))[t];
        a0x += v0.x; a0y += v0.y; a0z += v0.z; a0w += v0.w;
    }
    float ax = a0x + a1x + a2x + a3x;
    float ay = a0y + a1y + a2y + a3y;
    float az = a0z + a1z + a2z + a3z;
    float aw = a0w + a1w + a2w + a3w;
    int d = (cnt > 0) ? cnt : 1;
    float sc = TEMP_INV / (float)d;
    ushort4 o;
    o.x = f2bf(ax * sc); o.y = f2bf(ay * sc); o.z = f2bf(az * sc); o.w = f2bf(aw * sc);
    *(ushort4*)(FsumB + (size_t)c * DIM + t * 4) = o;
}

// ---------------- K3: MFMA bf16 GEMM: sims[b][c] = inputs[b] . FsumB[c] ----------------
// A = inputsB [256][1024], B^T = FsumB [8192][1024], C = sims [256][8192]
// BM=128: 8 MFMAs per 6 ds_reads per ks-step; B re-read 2x (was 4x); grid 128x2=256 blocks.
#define BM 128
#define BN 64
#define BK 64
#define LDT 72  // 64 + 8 pad (ushorts) -> 144B row stride, kills b128 bank conflicts

__global__ __launch_bounds__(256) void k_gemm(const unsigned short* __restrict__ A,
                                              const unsigned short* __restrict__ B,
                                              float* __restrict__ C) {
    __shared__ unsigned short As[BM * LDT];   // 18432 B
    __shared__ unsigned short Bs[BN * LDT];   // 9216 B
    int tid = threadIdx.x;
    int bn0 = blockIdx.x * BN;
    int bm0 = blockIdx.y * BM;
    int w = tid >> 6, lane = tid & 63;
    int quad = lane >> 4, l16 = lane & 15;
    int wm = (w >> 1) * 64;  // wave m-origin within block tile (0 or 64)
    int wn = (w & 1) * 32;   // wave n-origin (0 or 32)
    floatx4 acc[4][2];
    #pragma unroll
    for (int im = 0; im < 4; im++)
        #pragma unroll
        for (int in = 0; in < 2; in++)
            acc[im][in] = (floatx4){0.f, 0.f, 0.f, 0.f};

    int kg = tid & 7;   // k-group of 8 elements
    int rr = tid >> 3;  // 0..31

    for (int k0 = 0; k0 < DIM; k0 += BK) {
        // stage A tile: 128 x 64
        #pragma unroll
        for (int r = 0; r < 4; r++) {
            int m = rr + r * 32;
            uint4 v = *(const uint4*)(A + (size_t)(bm0 + m) * DIM + k0 + kg * 8);
            *(uint4*)&As[m * LDT + kg * 8] = v;
        }
        // stage B tile: 64 x 64
        #pragma unroll
        for (int r = 0; r < 2; r++) {
            int n = rr + r * 32;
            uint4 v = *(const uint4*)(B + (size_t)(bn0 + n) * DIM + k0 + kg * 8);
            *(uint4*)&Bs[n * LDT + kg * 8] = v;
        }
        __syncthreads();
        #pragma unroll
        for (int ks = 0; ks < BK; ks += 32) {
            short8 af[4], bf[2];
            #pragma unroll
            for (int im = 0; im < 4; im++)
                af[im] = *(const short8*)&As[(wm + im * 16 + l16) * LDT + ks + quad * 8];
            #pragma unroll
            for (int in = 0; in < 2; in++)
                bf[in] = *(const short8*)&Bs[(wn + in * 16 + l16) * LDT + ks + quad * 8];
            #pragma unroll
            for (int im = 0; im < 4; im++)
                #pragma unroll
                for (int in = 0; in < 2; in++)
                    acc[im][in] = __builtin_amdgcn_mfma_f32_16x16x32_bf16(af[im], bf[in], acc[im][in], 0, 0, 0);
        }
        __syncthreads();
    }
    // epilogue: D row = quad*4 + r (m), col = l16 (n)
    #pragma unroll
    for (int im = 0; im < 4; im++)
        #pragma unroll
        for (int in = 0; in < 2; in++) {
            int row = bm0 + wm + im * 16 + quad * 4;
            int col = bn0 + wn + in * 16 + l16;
            #pragma unroll
            for (int r = 0; r < 4; r++)
                C[(size_t)(row + r) * NCLUST + col] = acc[im][in][r];
        }
}

// ---------------- K4: truncated-softmax focal loss per row (radix-8 bisection select) ----------------
__global__ __launch_bounds__(256) void k_focal(const float* __restrict__ sims, const int* __restrict__ counts,
                                               const int* __restrict__ indexes, const int* __restrict__ labels,
                                               float* __restrict__ out) {
    __shared__ float lds4[4];
    __shared__ float lds7[4][8];
    __shared__ float s_et;
    int b = blockIdx.x, tid = threadIdx.x;
    int t = labels[indexes[b]];
    const float* srow = sims + (size_t)b * NCLUST;

    float X[32];
    float local = 0.f;
    #pragma unroll
    for (int r = 0; r < 8; r++) {
        int vi = r * 256 + tid;                      // float4 index in [0, 2048)
        float4 v = ((const float4*)srow)[vi];
        int4 cq = ((const int4*)counts)[vi];
        int i0 = vi * 4;
        float e0 = expf(v.x), e1 = expf(v.y), e2 = expf(v.z), e3 = expf(v.w);
        float x0 = (i0 + 0 == t || cq.x <= 0) ? 0.f : e0;
        float x1 = (i0 + 1 == t || cq.y <= 0) ? 0.f : e1;
        float x2 = (i0 + 2 == t || cq.z <= 0) ? 0.f : e2;
        float x3 = (i0 + 3 == t || cq.w <= 0) ? 0.f : e3;
        if (i0 + 0 == t) s_et = e0;                  // target cluster always non-empty
        if (i0 + 1 == t) s_et = e1;
        if (i0 + 2 == t) s_et = e2;
        if (i0 + 3 == t) s_et = e3;
        X[r * 4 + 0] = x0; X[r * 4 + 1] = x1; X[r * 4 + 2] = x2; X[r * 4 + 3] = x3;
        local += x0 + x1 + x2 + x3;
    }
    float S = block_sum(local, lds4);  // barriers inside also publish s_et
    float T = TOPP * S;

    // radix-8 bisection on float bit space: find boundary value x* (a data value)
    // invariant: G(lo) >= T, G(hi) < T, G(v) = sum of X >= v (non-increasing step fn)
    unsigned lo = 0u, hi = 0x7F800000u;
    for (int it = 0; it < 16 && (hi - lo) > 1u; it++) {
        unsigned range = hi - lo;
        unsigned step = range >> 3;
        if (step == 0u) step = 1u;
        float thr[7];
        #pragma unroll
        for (int k = 0; k < 7; k++) thr[k] = __uint_as_float(lo + (unsigned)(k + 1) * step);
        float g[7] = {0.f, 0.f, 0.f, 0.f, 0.f, 0.f, 0.f};
        #pragma unroll
        for (int r = 0; r < 32; r++) {
            float x = X[r];
            #pragma unroll
            for (int k = 0; k < 7; k++) g[k] += (x >= thr[k]) ? x : 0.f;
        }
        // fused 7-value block reduction: one barrier pair for all split points
        #pragma unroll
        for (int k = 0; k < 7; k++)
            for (int o = 32; o > 0; o >>= 1) g[k] += __shfl_down(g[k], o, 64);
        __syncthreads();
        if ((tid & 63) == 0) {
            #pragma unroll
            for (int k = 0; k < 7; k++) lds7[tid >> 6][k] = g[k];
        }
        __syncthreads();
        unsigned nlo = lo, nhi = hi;
        bool found = false;
        #pragma unroll
        for (int k = 0; k < 7; k++) {
            unsigned v = lo + (unsigned)(k + 1) * step;
            if (v < hi) {
                float G = lds7[0][k] + lds7[1][k] + lds7[2][k] + lds7[3][k];
                if (!found) {
                    if (G >= T) nlo = v;
                    else { nhi = v; found = true; }
                }
            }
        }
        lo = nlo; hi = nhi;
        __syncthreads();   // protect lds7 before next iteration overwrites
    }
    float xs = __uint_as_float(lo);  // actual data value, > 0

    float sgt = 0.f, sge = 0.f, cgt = 0.f;
    #pragma unroll
    for (int r = 0; r < 32; r++) {
        if (X[r] > xs) { sgt += X[r]; cgt += 1.f; }
        if (X[r] >= xs) sge += X[r];
    }
    sgt = block_sum(sgt, lds4);
    sge = block_sum(sge, lds4);
    cgt = block_sum(cgt, lds4);

    // crossing happens inside the run of values == xs:
    // csum candidates: sgt + j*xs, j = j0-1 and j0 (smallest j with sgt + j*xs >= T)
    float jf = (T - sgt) / xs;
    int j0 = (int)ceilf(jf);
    int mult = (int)rintf((sge - sgt) / xs);
    if (mult < 1) mult = 1;
    if (j0 < 1) j0 = 1;
    if (j0 > mult) j0 = mult;
    while (j0 > 1 && sgt + (float)(j0 - 1) * xs >= T) j0--;
    while (j0 < mult && sgt + (float)j0 * xs < T) j0++;
    float c_lo = sgt + (float)(j0 - 1) * xs;
    float c_hi = sgt + (float)j0 * xs;
    bool left_exists = ((int)cgt + j0) >= 2;                 // index i*-1 >= 0
    bool choose_left = left_exists && ((T - c_lo) <= (c_hi - T));  // argmin picks first on tie
    // if left candidate sits on the last element > x*, threshold = that element -> kept = sgt;
    // otherwise threshold = x* -> kept includes all ties -> sge
    float kept = (choose_left && j0 == 1) ? sgt : sge;

    if (tid == 0) {
        float et = s_et;
        float p = et / (et + kept + EPSC);
        float loss = -logf(p + EPSC);
        atomicAdd(out, loss * (1.0f / 256.0f));
    }
}

extern "C" void kernel_launch(void* const* d_in, const int* in_sizes, int n_in,
                              void* d_out, int out_size, void* d_ws, size_t ws_size,
                              hipStream_t stream) {
    const float* results = (const float*)d_in[0];
    const float* features = (const float*)d_in[1];
    const int* indexes = (const int*)d_in[2];
    const int* labels = (const int*)d_in[3];
    float* out = (float*)d_out;

    char* ws = (char*)d_ws;
    size_t off = 0;
    auto alloc = [&](size_t bytes) -> void* {
        void* p = ws + off;
        off += (bytes + 255) & ~(size_t)255;
        return p;
    };
    unsigned short* inputsB = (unsigned short*)alloc((size_t)BATCH * DIM * 2);
    unsigned short* FsumB = (unsigned short*)alloc((size_t)NCLUST * DIM * 2);
    float* sims = (float*)alloc((size_t)BATCH * NCLUST * 4);
    int* counts = (int*)alloc((size_t)NCLUST * 4);
    int* idxlist = (int*)alloc((size_t)NCLUST * CAP * 4);

    k_init<<<dim3(NCLUST / 256), dim3(256), 0, stream>>>(counts, out);
    k_prep<<<dim3(BATCH), dim3(256), 0, stream>>>(labels, counts, idxlist, results, inputsB);
    k_csum<<<dim3(NCLUST), dim3(256), 0, stream>>>(features, counts, idxlist, FsumB);
    k_gemm<<<dim3(NCLUST / BN, BATCH / BM), dim3(256), 0, stream>>>(inputsB, FsumB, sims);
    k_focal<<<dim3(BATCH), dim3(256), 0, stream>>>(sims, counts, indexes, labels, out);
}

// Round 3
// 416.206 us; speedup vs baseline: 1.1040x; 1.1040x over previous
//
#include <hip/hip_runtime.h>
#include <stdint.h>

#define NCLUST 8192
#define BATCH 256
#define DIM 1024
#define NFEAT 65536
#define TEMP_INV 20.0f
#define TOPP 0.1f
#define EPSC 1e-6f
#define CAP 64  // max rows per cluster slab; labels ~Poisson(8) over 8192 clusters (max ~30)

typedef __attribute__((ext_vector_type(8))) short short8;
typedef __attribute__((ext_vector_type(4))) float floatx4;

__device__ __forceinline__ unsigned short f2bf(float f) {
    uint32_t u = __float_as_uint(f);
    uint32_t r = u + 0x7FFFu + ((u >> 16) & 1u);
    return (unsigned short)(r >> 16);
}

__device__ __forceinline__ float block_sum(float v, float* lds4) {
    for (int o = 32; o > 0; o >>= 1) v += __shfl_down(v, o, 64);
    __syncthreads();                       // protect lds4 from previous use
    if ((threadIdx.x & 63) == 0) lds4[threadIdx.x >> 6] = v;
    __syncthreads();
    return lds4[0] + lds4[1] + lds4[2] + lds4[3];
}

__device__ __forceinline__ float block_max(float v, float* lds4) {
    for (int o = 32; o > 0; o >>= 1) v = fmaxf(v, __shfl_down(v, o, 64));
    __syncthreads();
    if ((threadIdx.x & 63) == 0) lds4[threadIdx.x >> 6] = v;
    __syncthreads();
    return fmaxf(fmaxf(lds4[0], lds4[1]), fmaxf(lds4[2], lds4[3]));
}

// ---------------- K0: zero counts + output ----------------
__global__ void k_init(int* counts, float* out) {
    int i = blockIdx.x * 256 + threadIdx.x;
    if (i < NCLUST) counts[i] = 0;
    if (i == 0) out[0] = 0.0f;
}

// ---------------- K1: fused scatter + L2-normalize ----------------
// Block b: scatters labels[b*256 .. +255] into per-cluster slabs AND normalizes
// results row b -> bf16. counts doubles as histogram (final value) and cursor.
__global__ void k_prep(const int* __restrict__ labels, int* __restrict__ counts,
                       int* __restrict__ idxlist,
                       const float* __restrict__ results, unsigned short* __restrict__ inputsB) {
    __shared__ float lds4[4];
    int b = blockIdx.x, t = threadIdx.x;
    // scatter part
    int n = b * 256 + t;
    int l = labels[n];
    int pos = atomicAdd(&counts[l], 1);
    if (pos < CAP) idxlist[l * CAP + pos] = n;
    // norm part
    const float4* rp = (const float4*)(results + (size_t)b * DIM);
    float4 v = rp[t];
    float ss = v.x * v.x + v.y * v.y + v.z * v.z + v.w * v.w;
    float S = block_sum(ss, lds4);
    float rn = rsqrtf(S);
    ushort4 o;
    o.x = f2bf(v.x * rn); o.y = f2bf(v.y * rn); o.z = f2bf(v.z * rn); o.w = f2bf(v.w * rn);
    *(ushort4*)(inputsB + (size_t)b * DIM + t * 4) = o;
}

// ---------------- K2: per-cluster feature sum, scale by 1/(TEMP*n), cast bf16 ----------------
__global__ __launch_bounds__(256) void k_csum(const float* __restrict__ features,
                                              const int* __restrict__ counts,
                                              const int* __restrict__ idxlist,
                                              unsigned short* __restrict__ FsumB) {
    int c = blockIdx.x, t = threadIdx.x;
    int cnt = counts[c];
    if (cnt > CAP) cnt = CAP;
    const int* lp = idxlist + c * CAP;
    float a0x = 0.f, a0y = 0.f, a0z = 0.f, a0w = 0.f;
    float a1x = 0.f, a1y = 0.f, a1z = 0.f, a1w = 0.f;
    float a2x = 0.f, a2y = 0.f, a2z = 0.f, a2w = 0.f;
    float a3x = 0.f, a3y = 0.f, a3z = 0.f, a3w = 0.f;
    int j = 0;
    for (; j + 4 <= cnt; j += 4) {
        int4 q = *(const int4*)(lp + j);   // 16B-aligned: CAP*4 = 256B slabs, j%4==0
        float4 v0 = ((const float4*)(features + (size_t)q.x * DIM))[t];
        float4 v1 = ((const float4*)(features + (size_t)q.y * DIM))[t];
        float4 v2 = ((const float4*)(features + (size_t)q.z * DIM))[t];
        float4 v3 = ((const float4*)(features + (size_t)q.w * DIM))[t];
        a0x += v0.x; a0y += v0.y; a0z += v0.z; a0w += v0.w;
        a1x += v1.x; a1y += v1.y; a1z += v1.z; a1w += v1.w;
        a2x += v2.x; a2y += v2.y; a2z += v2.z; a2w += v2.w;
        a3x += v3.x; a3y += v3.y; a3z += v3.z; a3w += v3.w;
    }
    for (; j < cnt; j++) {
        int r0 = lp[j];
        float4 v0 = ((const float4*)(features + (size_t)r0 * DIM))[t];
        a0x += v0.x; a0y += v0.y; a0z += v0.z; a0w += v0.w;
    }
    float ax = a0x + a1x + a2x + a3x;
    float ay = a0y + a1y + a2y + a3y;
    float az = a0z + a1z + a2z + a3z;
    float aw = a0w + a1w + a2w + a3w;
    int d = (cnt > 0) ? cnt : 1;
    float sc = TEMP_INV / (float)d;
    ushort4 o;
    o.x = f2bf(ax * sc); o.y = f2bf(ay * sc); o.z = f2bf(az * sc); o.w = f2bf(aw * sc);
    *(ushort4*)(FsumB + (size_t)c * DIM + t * 4) = o;
}

// ---------------- K3: MFMA bf16 GEMM: sims[b][c] = inputs[b] . FsumB[c] ----------------
// A = inputsB [256][1024], B^T = FsumB [8192][1024], C = sims [256][8192]
// 64x64 tile (proven R1 occupancy: 512 blocks = 2/CU), BK=128 halves barrier count.
// MFMA k-order unchanged (ascending 32-slices) -> bitwise-identical sims.
#define BM 64
#define BN 64
#define BK 128
#define LDT 136  // 128 + 8 pad (ushorts) -> 272B row stride, 2-way-max bank aliasing on b128

__global__ __launch_bounds__(256) void k_gemm(const unsigned short* __restrict__ A,
                                              const unsigned short* __restrict__ B,
                                              float* __restrict__ C) {
    __shared__ unsigned short As[BM * LDT];   // 17408 B
    __shared__ unsigned short Bs[BN * LDT];   // 17408 B
    int tid = threadIdx.x;
    int bn0 = blockIdx.x * BN;
    int bm0 = blockIdx.y * BM;
    int w = tid >> 6, lane = tid & 63;
    int quad = lane >> 4, l16 = lane & 15;
    int wm = (w >> 1) * 32;  // wave m-origin within block tile
    int wn = (w & 1) * 32;   // wave n-origin
    floatx4 acc[2][2];
    #pragma unroll
    for (int im = 0; im < 2; im++)
        #pragma unroll
        for (int in = 0; in < 2; in++)
            acc[im][in] = (floatx4){0.f, 0.f, 0.f, 0.f};

    int kg = tid & 15;  // k-group of 8 elements (16 groups cover BK=128)
    int rr = tid >> 4;  // 0..15

    for (int k0 = 0; k0 < DIM; k0 += BK) {
        // stage A tile: 64 x 128
        #pragma unroll
        for (int r = 0; r < 4; r++) {
            int m = rr + r * 16;
            uint4 v = *(const uint4*)(A + (size_t)(bm0 + m) * DIM + k0 + kg * 8);
            *(uint4*)&As[m * LDT + kg * 8] = v;
        }
        // stage B tile: 64 x 128
        #pragma unroll
        for (int r = 0; r < 4; r++) {
            int n = rr + r * 16;
            uint4 v = *(const uint4*)(B + (size_t)(bn0 + n) * DIM + k0 + kg * 8);
            *(uint4*)&Bs[n * LDT + kg * 8] = v;
        }
        __syncthreads();
        #pragma unroll
        for (int ks = 0; ks < BK; ks += 32) {
            short8 af[2], bf[2];
            #pragma unroll
            for (int im = 0; im < 2; im++)
                af[im] = *(const short8*)&As[(wm + im * 16 + l16) * LDT + ks + quad * 8];
            #pragma unroll
            for (int in = 0; in < 2; in++)
                bf[in] = *(const short8*)&Bs[(wn + in * 16 + l16) * LDT + ks + quad * 8];
            #pragma unroll
            for (int im = 0; im < 2; im++)
                #pragma unroll
                for (int in = 0; in < 2; in++)
                    acc[im][in] = __builtin_amdgcn_mfma_f32_16x16x32_bf16(af[im], bf[in], acc[im][in], 0, 0, 0);
        }
        __syncthreads();
    }
    // epilogue: D row = quad*4 + r (m), col = l16 (n)
    #pragma unroll
    for (int im = 0; im < 2; im++)
        #pragma unroll
        for (int in = 0; in < 2; in++) {
            int row = bm0 + wm + im * 16 + quad * 4;
            int col = bn0 + wn + in * 16 + l16;
            #pragma unroll
            for (int r = 0; r < 4; r++)
                C[(size_t)(row + r) * NCLUST + col] = acc[im][in][r];
        }
}

// ---------------- K4: truncated-softmax focal loss per row (radix-2 bisection, tight bounds) ----------------
__global__ __launch_bounds__(256) void k_focal(const float* __restrict__ sims, const int* __restrict__ counts,
                                               const int* __restrict__ indexes, const int* __restrict__ labels,
                                               float* __restrict__ out) {
    __shared__ float lds4[4];
    __shared__ float s_et;
    int b = blockIdx.x, tid = threadIdx.x;
    int t = labels[indexes[b]];
    const float* srow = sims + (size_t)b * NCLUST;

    float X[32];
    float local = 0.f, lmax = 0.f;
    #pragma unroll
    for (int r = 0; r < 8; r++) {
        int vi = r * 256 + tid;                      // float4 index in [0, 2048)
        float4 v = ((const float4*)srow)[vi];
        int4 cq = ((const int4*)counts)[vi];
        int i0 = vi * 4;
        float e0 = expf(v.x), e1 = expf(v.y), e2 = expf(v.z), e3 = expf(v.w);
        float x0 = (i0 + 0 == t || cq.x <= 0) ? 0.f : e0;
        float x1 = (i0 + 1 == t || cq.y <= 0) ? 0.f : e1;
        float x2 = (i0 + 2 == t || cq.z <= 0) ? 0.f : e2;
        float x3 = (i0 + 3 == t || cq.w <= 0) ? 0.f : e3;
        if (i0 + 0 == t) s_et = e0;                  // target cluster always non-empty
        if (i0 + 1 == t) s_et = e1;
        if (i0 + 2 == t) s_et = e2;
        if (i0 + 3 == t) s_et = e3;
        X[r * 4 + 0] = x0; X[r * 4 + 1] = x1; X[r * 4 + 2] = x2; X[r * 4 + 3] = x3;
        local += x0 + x1 + x2 + x3;
        lmax = fmaxf(fmaxf(lmax, fmaxf(x0, x1)), fmaxf(x2, x3));
    }
    float S = block_sum(local, lds4);  // barriers inside also publish s_et
    float M = block_max(lmax, lds4);
    float T = TOPP * S;

    // bisection on float bit space: find boundary value x* where desc-cumsum crosses T
    // invariants: G(lo) >= T, G(hi) < T.
    //   lo0 = bits(T/8192): G(v) > S - 8192*v => G(lo0) > 0.9*S >= T.
    //   hi0 = bits(maxX)+1: G there = 0 < T.
    unsigned lo = __float_as_uint(T * (1.0f / 8192.0f));
    unsigned hi = __float_as_uint(M) + 1u;
    for (int it = 0; it < 31 && (hi - lo) > 1u; it++) {
        unsigned mid = lo + ((hi - lo) >> 1);
        float v = __uint_as_float(mid);
        float g = 0.f;
        #pragma unroll
        for (int r = 0; r < 32; r++) g += (X[r] >= v) ? X[r] : 0.f;
        g = block_sum(g, lds4);
        if (g >= T) lo = mid; else hi = mid;
    }
    float xs = __uint_as_float(lo);  // actual data value, > 0

    float sgt = 0.f, sge = 0.f, cgt = 0.f;
    #pragma unroll
    for (int r = 0; r < 32; r++) {
        if (X[r] > xs) { sgt += X[r]; cgt += 1.f; }
        if (X[r] >= xs) sge += X[r];
    }
    sgt = block_sum(sgt, lds4);
    sge = block_sum(sge, lds4);
    cgt = block_sum(cgt, lds4);

    // crossing happens inside the run of values == xs:
    // csum candidates: sgt + j*xs, j = j0-1 and j0 (smallest j with sgt + j*xs >= T)
    float jf = (T - sgt) / xs;
    int j0 = (int)ceilf(jf);
    int mult = (int)rintf((sge - sgt) / xs);
    if (mult < 1) mult = 1;
    if (j0 < 1) j0 = 1;
    if (j0 > mult) j0 = mult;
    while (j0 > 1 && sgt + (float)(j0 - 1) * xs >= T) j0--;
    while (j0 < mult && sgt + (float)j0 * xs < T) j0++;
    float c_lo = sgt + (float)(j0 - 1) * xs;
    float c_hi = sgt + (float)j0 * xs;
    bool left_exists = ((int)cgt + j0) >= 2;                 // index i*-1 >= 0
    bool choose_left = left_exists && ((T - c_lo) <= (c_hi - T));  // argmin picks first on tie
    // if left candidate sits on the last element > x*, threshold = that element -> kept = sgt;
    // otherwise threshold = x* -> kept includes all ties -> sge
    float kept = (choose_left && j0 == 1) ? sgt : sge;

    if (tid == 0) {
        float et = s_et;
        float p = et / (et + kept + EPSC);
        float loss = -logf(p + EPSC);
        atomicAdd(out, loss * (1.0f / 256.0f));
    }
}

extern "C" void kernel_launch(void* const* d_in, const int* in_sizes, int n_in,
                              void* d_out, int out_size, void* d_ws, size_t ws_size,
                              hipStream_t stream) {
    const float* results = (const float*)d_in[0];
    const float* features = (const float*)d_in[1];
    const int* indexes = (const int*)d_in[2];
    const int* labels = (const int*)d_in[3];
    float* out = (float*)d_out;

    char* ws = (char*)d_ws;
    size_t off = 0;
    auto alloc = [&](size_t bytes) -> void* {
        void* p = ws + off;
        off += (bytes + 255) & ~(size_t)255;
        return p;
    };
    unsigned short* inputsB = (unsigned short*)alloc((size_t)BATCH * DIM * 2);
    unsigned short* FsumB = (unsigned short*)alloc((size_t)NCLUST * DIM * 2);
    float* sims = (float*)alloc((size_t)BATCH * NCLUST * 4);
    int* counts = (int*)alloc((size_t)NCLUST * 4);
    int* idxlist = (int*)alloc((size_t)NCLUST * CAP * 4);

    k_init<<<dim3(NCLUST / 256), dim3(256), 0, stream>>>(counts, out);
    k_prep<<<dim3(BATCH), dim3(256), 0, stream>>>(labels, counts, idxlist, results, inputsB);
    k_csum<<<dim3(NCLUST), dim3(256), 0, stream>>>(features, counts, idxlist, FsumB);
    k_gemm<<<dim3(NCLUST / BN, BATCH / BM), dim3(256), 0, stream>>>(inputsB, FsumB, sims);
    k_focal<<<dim3(BATCH), dim3(256), 0, stream>>>(sims, counts, indexes, labels, out);
}

// Round 4
// 414.144 us; speedup vs baseline: 1.1095x; 1.0050x over previous
//
#include <hip/hip_runtime.h>
#include <stdint.h>

#define NCLUST 8192
#define BATCH 256
#define DIM 1024
#define NFEAT 65536
#define TEMP_INV 20.0f
#define TOPP 0.1f
#define EPSC 1e-6f
#define CAP 64  // max rows per cluster slab; labels ~Poisson(8) over 8192 clusters (max ~30)

typedef __attribute__((ext_vector_type(8))) short short8;
typedef __attribute__((ext_vector_type(4))) float floatx4;

__device__ __forceinline__ unsigned short f2bf(float f) {
    uint32_t u = __float_as_uint(f);
    uint32_t r = u + 0x7FFFu + ((u >> 16) & 1u);
    return (unsigned short)(r >> 16);
}

__device__ __forceinline__ float block_sum(float v, float* lds4) {
    for (int o = 32; o > 0; o >>= 1) v += __shfl_down(v, o, 64);
    __syncthreads();                       // protect lds4 from previous use
    if ((threadIdx.x & 63) == 0) lds4[threadIdx.x >> 6] = v;
    __syncthreads();
    return lds4[0] + lds4[1] + lds4[2] + lds4[3];
}

__device__ __forceinline__ float block_max(float v, float* lds4) {
    for (int o = 32; o > 0; o >>= 1) v = fmaxf(v, __shfl_down(v, o, 64));
    __syncthreads();
    if ((threadIdx.x & 63) == 0) lds4[threadIdx.x >> 6] = v;
    __syncthreads();
    return fmaxf(fmaxf(lds4[0], lds4[1]), fmaxf(lds4[2], lds4[3]));
}

// async global->LDS, 16B per lane; dest = wave-uniform base + lane*16 (HW rule)
__device__ __forceinline__ void gload16(const unsigned short* gp, unsigned short* lp) {
    __builtin_amdgcn_global_load_lds(
        (const __attribute__((address_space(1))) unsigned int*)(const void*)gp,
        (__attribute__((address_space(3))) unsigned int*)(void*)lp, 16, 0, 0);
}

// ---------------- K0: zero counts + output ----------------
__global__ void k_init(int* counts, float* out) {
    int i = blockIdx.x * 256 + threadIdx.x;
    if (i < NCLUST) counts[i] = 0;
    if (i == 0) out[0] = 0.0f;
}

// ---------------- K1: fused scatter + L2-normalize ----------------
__global__ void k_prep(const int* __restrict__ labels, int* __restrict__ counts,
                       int* __restrict__ idxlist,
                       const float* __restrict__ results, unsigned short* __restrict__ inputsB) {
    __shared__ float lds4[4];
    int b = blockIdx.x, t = threadIdx.x;
    // scatter part
    int n = b * 256 + t;
    int l = labels[n];
    int pos = atomicAdd(&counts[l], 1);
    if (pos < CAP) idxlist[l * CAP + pos] = n;
    // norm part
    const float4* rp = (const float4*)(results + (size_t)b * DIM);
    float4 v = rp[t];
    float ss = v.x * v.x + v.y * v.y + v.z * v.z + v.w * v.w;
    float S = block_sum(ss, lds4);
    float rn = rsqrtf(S);
    ushort4 o;
    o.x = f2bf(v.x * rn); o.y = f2bf(v.y * rn); o.z = f2bf(v.z * rn); o.w = f2bf(v.w * rn);
    *(ushort4*)(inputsB + (size_t)b * DIM + t * 4) = o;
}

// ---------------- K2: per-cluster feature sum, scale by 1/(TEMP*n), cast bf16 ----------------
__global__ __launch_bounds__(256) void k_csum(const float* __restrict__ features,
                                              const int* __restrict__ counts,
                                              const int* __restrict__ idxlist,
                                              unsigned short* __restrict__ FsumB) {
    int c = blockIdx.x, t = threadIdx.x;
    int cnt = counts[c];
    if (cnt > CAP) cnt = CAP;
    const int* lp = idxlist + c * CAP;
    float a0x = 0.f, a0y = 0.f, a0z = 0.f, a0w = 0.f;
    float a1x = 0.f, a1y = 0.f, a1z = 0.f, a1w = 0.f;
    float a2x = 0.f, a2y = 0.f, a2z = 0.f, a2w = 0.f;
    float a3x = 0.f, a3y = 0.f, a3z = 0.f, a3w = 0.f;
    int j = 0;
    for (; j + 4 <= cnt; j += 4) {
        int4 q = *(const int4*)(lp + j);   // 16B-aligned: CAP*4 = 256B slabs, j%4==0
        float4 v0 = ((const float4*)(features + (size_t)q.x * DIM))[t];
        float4 v1 = ((const float4*)(features + (size_t)q.y * DIM))[t];
        float4 v2 = ((const float4*)(features + (size_t)q.z * DIM))[t];
        float4 v3 = ((const float4*)(features + (size_t)q.w * DIM))[t];
        a0x += v0.x; a0y += v0.y; a0z += v0.z; a0w += v0.w;
        a1x += v1.x; a1y += v1.y; a1z += v1.z; a1w += v1.w;
        a2x += v2.x; a2y += v2.y; a2z += v2.z; a2w += v2.w;
        a3x += v3.x; a3y += v3.y; a3z += v3.z; a3w += v3.w;
    }
    for (; j < cnt; j++) {
        int r0 = lp[j];
        float4 v0 = ((const float4*)(features + (size_t)r0 * DIM))[t];
        a0x += v0.x; a0y += v0.y; a0z += v0.z; a0w += v0.w;
    }
    float ax = a0x + a1x + a2x + a3x;
    float ay = a0y + a1y + a2y + a3y;
    float az = a0z + a1z + a2z + a3z;
    float aw = a0w + a1w + a2w + a3w;
    int d = (cnt > 0) ? cnt : 1;
    float sc = TEMP_INV / (float)d;
    ushort4 o;
    o.x = f2bf(ax * sc); o.y = f2bf(ay * sc); o.z = f2bf(az * sc); o.w = f2bf(aw * sc);
    *(ushort4*)(FsumB + (size_t)c * DIM + t * 4) = o;
}

// ---------------- K3: MFMA bf16 GEMM via global_load_lds + XOR swizzle ----------------
// A = inputsB [256][1024], B^T = FsumB [8192][1024], C = sims [256][8192]
// Linear LDS tiles; staging pre-swizzles the GLOBAL source chunk (kg ^ (row&7)),
// reads apply the same involution -> 2-way max bank aliasing (free), data fed to
// each MFMA is byte-identical to the padded reg-staged version (bitwise-same sims).
// BK=256: 4 K-steps, 4 barrier pairs per block (was 8).
#define BM 64
#define BN 64
#define BK 256

__global__ __launch_bounds__(256) void k_gemm(const unsigned short* __restrict__ A,
                                              const unsigned short* __restrict__ B,
                                              float* __restrict__ C) {
    __shared__ unsigned short As[BM * BK];   // 32 KB
    __shared__ unsigned short Bs[BN * BK];   // 32 KB
    int tid = threadIdx.x;
    int bn0 = blockIdx.x * BN;
    int bm0 = blockIdx.y * BM;
    int w = tid >> 6, lane = tid & 63;
    int quad = lane >> 4, l16 = lane & 15;
    int wm = (w >> 1) * 32;  // wave m-origin within block tile
    int wn = (w & 1) * 32;   // wave n-origin
    floatx4 acc[2][2];
    #pragma unroll
    for (int im = 0; im < 2; im++)
        #pragma unroll
        for (int in = 0; in < 2; in++)
            acc[im][in] = (floatx4){0.f, 0.f, 0.f, 0.f};

    int sm = lane >> 5;   // 0..1: row within the wave's 2-row slab
    int kg = lane & 31;   // 16B chunk within a 512B row

    for (int k0 = 0; k0 < DIM; k0 += BK) {   // 4 iterations
        // stage A tile 64x256: wave w, slab r covers rows r*8 + w*2 + {0,1}
        #pragma unroll
        for (int r = 0; r < 8; r++) {
            int m = r * 8 + w * 2 + sm;
            int kp = kg ^ (m & 7);           // pre-swizzled source chunk
            gload16(A + (size_t)(bm0 + m) * DIM + k0 + kp * 8, &As[(r * 8 + w * 2) * BK]);
        }
        // stage B tile 64x256
        #pragma unroll
        for (int r = 0; r < 8; r++) {
            int n = r * 8 + w * 2 + sm;
            int kp = kg ^ (n & 7);
            gload16(B + (size_t)(bn0 + n) * DIM + k0 + kp * 8, &Bs[(r * 8 + w * 2) * BK]);
        }
        __syncthreads();                     // compiler drains vmcnt before barrier
        #pragma unroll
        for (int ks = 0; ks < BK; ks += 32) {
            short8 af[2], bf[2];
            #pragma unroll
            for (int im = 0; im < 2; im++) {
                int row = wm + im * 16 + l16;
                af[im] = *(const short8*)&As[row * BK + (((ks >> 3) + quad) ^ (row & 7)) * 8];
            }
            #pragma unroll
            for (int in = 0; in < 2; in++) {
                int row = wn + in * 16 + l16;
                bf[in] = *(const short8*)&Bs[row * BK + (((ks >> 3) + quad) ^ (row & 7)) * 8];
            }
            #pragma unroll
            for (int im = 0; im < 2; im++)
                #pragma unroll
                for (int in = 0; in < 2; in++)
                    acc[im][in] = __builtin_amdgcn_mfma_f32_16x16x32_bf16(af[im], bf[in], acc[im][in], 0, 0, 0);
        }
        __syncthreads();
    }
    // epilogue: D row = quad*4 + r (m), col = l16 (n)
    #pragma unroll
    for (int im = 0; im < 2; im++)
        #pragma unroll
        for (int in = 0; in < 2; in++) {
            int row = bm0 + wm + im * 16 + quad * 4;
            int col = bn0 + wn + in * 16 + l16;
            #pragma unroll
            for (int r = 0; r < 4; r++)
                C[(size_t)(row + r) * NCLUST + col] = acc[im][in][r];
        }
}

// ---------------- K4: truncated-softmax focal loss per row (radix-2 bisection, tight bounds) ----------------
__global__ __launch_bounds__(256) void k_focal(const float* __restrict__ sims, const int* __restrict__ counts,
                                               const int* __restrict__ indexes, const int* __restrict__ labels,
                                               float* __restrict__ out) {
    __shared__ float lds4[4];
    __shared__ float s_et;
    int b = blockIdx.x, tid = threadIdx.x;
    int t = labels[indexes[b]];
    const float* srow = sims + (size_t)b * NCLUST;

    float X[32];
    float local = 0.f, lmax = 0.f;
    #pragma unroll
    for (int r = 0; r < 8; r++) {
        int vi = r * 256 + tid;                      // float4 index in [0, 2048)
        float4 v = ((const float4*)srow)[vi];
        int4 cq = ((const int4*)counts)[vi];
        int i0 = vi * 4;
        float e0 = expf(v.x), e1 = expf(v.y), e2 = expf(v.z), e3 = expf(v.w);
        float x0 = (i0 + 0 == t || cq.x <= 0) ? 0.f : e0;
        float x1 = (i0 + 1 == t || cq.y <= 0) ? 0.f : e1;
        float x2 = (i0 + 2 == t || cq.z <= 0) ? 0.f : e2;
        float x3 = (i0 + 3 == t || cq.w <= 0) ? 0.f : e3;
        if (i0 + 0 == t) s_et = e0;                  // target cluster always non-empty
        if (i0 + 1 == t) s_et = e1;
        if (i0 + 2 == t) s_et = e2;
        if (i0 + 3 == t) s_et = e3;
        X[r * 4 + 0] = x0; X[r * 4 + 1] = x1; X[r * 4 + 2] = x2; X[r * 4 + 3] = x3;
        local += x0 + x1 + x2 + x3;
        lmax = fmaxf(fmaxf(lmax, fmaxf(x0, x1)), fmaxf(x2, x3));
    }
    float S = block_sum(local, lds4);  // barriers inside also publish s_et
    float M = block_max(lmax, lds4);
    float T = TOPP * S;

    // bisection on float bit space: find boundary value x* where desc-cumsum crosses T
    // invariants: G(lo) >= T, G(hi) < T.
    unsigned lo = __float_as_uint(T * (1.0f / 8192.0f));
    unsigned hi = __float_as_uint(M) + 1u;
    for (int it = 0; it < 31 && (hi - lo) > 1u; it++) {
        unsigned mid = lo + ((hi - lo) >> 1);
        float v = __uint_as_float(mid);
        float g = 0.f;
        #pragma unroll
        for (int r = 0; r < 32; r++) g += (X[r] >= v) ? X[r] : 0.f;
        g = block_sum(g, lds4);
        if (g >= T) lo = mid; else hi = mid;
    }
    float xs = __uint_as_float(lo);  // actual data value, > 0

    float sgt = 0.f, sge = 0.f, cgt = 0.f;
    #pragma unroll
    for (int r = 0; r < 32; r++) {
        if (X[r] > xs) { sgt += X[r]; cgt += 1.f; }
        if (X[r] >= xs) sge += X[r];
    }
    sgt = block_sum(sgt, lds4);
    sge = block_sum(sge, lds4);
    cgt = block_sum(cgt, lds4);

    // crossing happens inside the run of values == xs:
    float jf = (T - sgt) / xs;
    int j0 = (int)ceilf(jf);
    int mult = (int)rintf((sge - sgt) / xs);
    if (mult < 1) mult = 1;
    if (j0 < 1) j0 = 1;
    if (j0 > mult) j0 = mult;
    while (j0 > 1 && sgt + (float)(j0 - 1) * xs >= T) j0--;
    while (j0 < mult && sgt + (float)j0 * xs < T) j0++;
    float c_lo = sgt + (float)(j0 - 1) * xs;
    float c_hi = sgt + (float)j0 * xs;
    bool left_exists = ((int)cgt + j0) >= 2;                 // index i*-1 >= 0
    bool choose_left = left_exists && ((T - c_lo) <= (c_hi - T));  // argmin picks first on tie
    float kept = (choose_left && j0 == 1) ? sgt : sge;

    if (tid == 0) {
        float et = s_et;
        float p = et / (et + kept + EPSC);
        float loss = -logf(p + EPSC);
        atomicAdd(out, loss * (1.0f / 256.0f));
    }
}

extern "C" void kernel_launch(void* const* d_in, const int* in_sizes, int n_in,
                              void* d_out, int out_size, void* d_ws, size_t ws_size,
                              hipStream_t stream) {
    const float* results = (const float*)d_in[0];
    const float* features = (const float*)d_in[1];
    const int* indexes = (const int*)d_in[2];
    const int* labels = (const int*)d_in[3];
    float* out = (float*)d_out;

    char* ws = (char*)d_ws;
    size_t off = 0;
    auto alloc = [&](size_t bytes) -> void* {
        void* p = ws + off;
        off += (bytes + 255) & ~(size_t)255;
        return p;
    };
    unsigned short* inputsB = (unsigned short*)alloc((size_t)BATCH * DIM * 2);
    unsigned short* FsumB = (unsigned short*)alloc((size_t)NCLUST * DIM * 2);
    float* sims = (float*)alloc((size_t)BATCH * NCLUST * 4);
    int* counts = (int*)alloc((size_t)NCLUST * 4);
    int* idxlist = (int*)alloc((size_t)NCLUST * CAP * 4);

    k_init<<<dim3(NCLUST / 256), dim3(256), 0, stream>>>(counts, out);
    k_prep<<<dim3(BATCH), dim3(256), 0, stream>>>(labels, counts, idxlist, results, inputsB);
    k_csum<<<dim3(NCLUST), dim3(256), 0, stream>>>(features, counts, idxlist, FsumB);
    k_gemm<<<dim3(NCLUST / BN, BATCH / BM), dim3(256), 0, stream>>>(inputsB, FsumB, sims);
    k_focal<<<dim3(BATCH), dim3(256), 0, stream>>>(sims, counts, indexes, labels, out);
}